// Round 1
// baseline (1590.224 us; speedup 1.0000x reference)
//
#include <hip/hip_runtime.h>

#define NHEADS 16      // B*H
#define SEQ    4096
#define DIM    64
#define CHUNK  128
#define NC     32      // SEQ/CHUNK
#define EPSV   1e-10f

// Workspace layout (floats):
//   S    : [2][16][32][64*64]  chunk outer-product states -> exclusive prefix
//   ksum : offset 4194304, [2][16][32][64]
#define KS_OFF 4194304

// ---------------- Pass A: per-chunk states ----------------
__global__ __launch_bounds__(256) void pass_a(const float* __restrict__ k0,
                                              const float* __restrict__ k1,
                                              const float* __restrict__ v,
                                              float* __restrict__ ws) {
  int bid = blockIdx.x;                 // m*512 + hh*32 + c
  int m = bid >> 9, rem = bid & 511, hh = rem >> 5, c = rem & 31;
  const float* kp = (m ? k1 : k0) + (size_t)hh * SEQ * DIM + (size_t)c * CHUNK * DIM;
  const float* vp = v + (size_t)hh * SEQ * DIM + (size_t)c * CHUNK * DIM;

  __shared__ float sk[CHUNK * DIM];
  __shared__ float sv[CHUNK * DIM];
  int tid = threadIdx.x;
  for (int idx = tid; idx < CHUNK * DIM / 4; idx += 256) {
    ((float4*)sk)[idx] = ((const float4*)kp)[idx];
    ((float4*)sv)[idx] = ((const float4*)vp)[idx];
  }
  __syncthreads();

  int d0 = (tid >> 4) * 4, e0 = (tid & 15) * 4;
  float acc[4][4] = {};
  for (int j = 0; j < CHUNK; ++j) {
    float4 kd = *(const float4*)&sk[j * DIM + d0];
    float4 ve = *(const float4*)&sv[j * DIM + e0];
    float ka[4] = {kd.x, kd.y, kd.z, kd.w};
    float va[4] = {ve.x, ve.y, ve.z, ve.w};
#pragma unroll
    for (int a = 0; a < 4; ++a)
#pragma unroll
      for (int b = 0; b < 4; ++b) acc[a][b] += ka[a] * va[b];
  }
  float* Sp = ws + (size_t)bid * 4096;
#pragma unroll
  for (int a = 0; a < 4; ++a)
#pragma unroll
    for (int b = 0; b < 4; ++b) Sp[(d0 + a) * 64 + e0 + b] = acc[a][b];

  if (tid < 64) {
    float s = 0.f;
    for (int j = 0; j < CHUNK; ++j) s += sk[j * DIM + tid];
    ws[KS_OFF + (size_t)bid * 64 + tid] = s;
  }
}

// ---------------- Pass B: exclusive prefix over chunks ----------------
__global__ __launch_bounds__(256) void pass_b(float* __restrict__ ws) {
  int t = blockIdx.x * 256 + threadIdx.x;
  if (blockIdx.x < 512) {            // S lanes: [m*16+hh][de]
    int mh = t >> 12, de = t & 4095;
    float* p = ws + (size_t)mh * NC * 4096 + de;
    float run = 0.f;
    for (int c = 0; c < NC; ++c) {
      float x = p[(size_t)c * 4096];
      p[(size_t)c * 4096] = run;
      run += x;
    }
  } else {                           // ksum lanes
    int t2 = t - 512 * 256;          // [0, 2048)
    int mh = t2 >> 6, d = t2 & 63;
    float* p = ws + KS_OFF + (size_t)mh * NC * 64 + d;
    float run = 0.f;
    for (int c = 0; c < NC; ++c) {
      float x = p[(size_t)c * 64];
      p[(size_t)c * 64] = run;
      run += x;
    }
  }
}

// ---------------- Pass C: per-chunk output ----------------
__global__ __launch_bounds__(128) void pass_c(const float* __restrict__ q0,
                                              const float* __restrict__ q1,
                                              const float* __restrict__ k0,
                                              const float* __restrict__ k1,
                                              const float* __restrict__ v,
                                              const float* __restrict__ ws,
                                              float* __restrict__ out) {
  int hh = blockIdx.x >> 5, c = blockIdx.x & 31;
  int i = threadIdx.x;  // row within chunk

  __shared__ float sk[CHUNK * DIM];  // 32 KiB (holds S, then k)
  __shared__ float sv[CHUNK * DIM];  // 32 KiB (holds ksum, then v)

  float4 acc[16];
#pragma unroll
  for (int t = 0; t < 16; ++t) acc[t] = make_float4(0.f, 0.f, 0.f, 0.f);
  float den = 0.f;

  for (int m = 0; m < 2; ++m) {
    const float* qp = (m ? q1 : q0) + (size_t)hh * SEQ * DIM + (size_t)c * CHUNK * DIM;
    const float* kp = (m ? k1 : k0) + (size_t)hh * SEQ * DIM + (size_t)c * CHUNK * DIM;
    const float* vp = v + (size_t)hh * SEQ * DIM + (size_t)c * CHUNK * DIM;
    const float* Sp = ws + (size_t)(m * 512 + hh * 32 + c) * 4096;
    const float* Kp = ws + KS_OFF + (size_t)(m * 512 + hh * 32 + c) * 64;

    __syncthreads();  // protect LDS reuse from previous map iteration
    for (int idx = i; idx < 4096 / 4; idx += 128) ((float4*)sk)[idx] = ((const float4*)Sp)[idx];
    if (i < 16) ((float4*)sv)[i] = ((const float4*)Kp)[i];
    __syncthreads();

    // q row -> registers
    float4 qv[16];
#pragma unroll
    for (int t = 0; t < 16; ++t) qv[t] = ((const float4*)(qp + (size_t)i * DIM))[t];

    // inter = q_i @ S_prefix ; den += q_i . ksum_prefix
#pragma unroll
    for (int d4 = 0; d4 < 16; ++d4) {
      float4 qq = qv[d4];
      float qs[4] = {qq.x, qq.y, qq.z, qq.w};
#pragma unroll
      for (int u = 0; u < 4; ++u) {
        int d = d4 * 4 + u;
        float qd = qs[u];
        den += qd * sv[d];
#pragma unroll
        for (int t = 0; t < 16; ++t) {
          float4 s4 = *(const float4*)&sk[d * 64 + t * 4];
          acc[t].x += qd * s4.x;
          acc[t].y += qd * s4.y;
          acc[t].z += qd * s4.z;
          acc[t].w += qd * s4.w;
        }
      }
    }

    __syncthreads();
    for (int idx = i; idx < CHUNK * DIM / 4; idx += 128) {
      ((float4*)sk)[idx] = ((const float4*)kp)[idx];
      ((float4*)sv)[idx] = ((const float4*)vp)[idx];
    }
    __syncthreads();

    // intra: masked scores + value accumulation + denominator row-sum
    for (int j = 0; j < CHUNK; ++j) {
      if (j <= i) {
        float s = 0.f;
#pragma unroll
        for (int t = 0; t < 16; ++t) {
          float4 kk = *(const float4*)&sk[j * DIM + t * 4];
          float4 qq = qv[t];
          s += qq.x * kk.x + qq.y * kk.y + qq.z * kk.z + qq.w * kk.w;
        }
        den += s;
#pragma unroll
        for (int t = 0; t < 16; ++t) {
          float4 vv = *(const float4*)&sv[j * DIM + t * 4];
          acc[t].x += s * vv.x;
          acc[t].y += s * vv.y;
          acc[t].z += s * vv.z;
          acc[t].w += s * vv.w;
        }
      }
    }
  }

  float inv = 1.f / (den + EPSV);
  float* op = out + (size_t)hh * SEQ * DIM + (size_t)c * CHUNK * DIM + (size_t)i * DIM;
#pragma unroll
  for (int t = 0; t < 16; ++t) {
    float4 r;
    r.x = acc[t].x * inv;
    r.y = acc[t].y * inv;
    r.z = acc[t].z * inv;
    r.w = acc[t].w * inv;
    ((float4*)op)[t] = r;
  }
}

extern "C" void kernel_launch(void* const* d_in, const int* in_sizes, int n_in,
                              void* d_out, int out_size, void* d_ws, size_t ws_size,
                              hipStream_t stream) {
  const float* q  = (const float*)d_in[0];
  const float* k  = (const float*)d_in[1];
  const float* qr = (const float*)d_in[2];
  const float* kr = (const float*)d_in[3];
  const float* v  = (const float*)d_in[4];
  float* out = (float*)d_out;
  float* ws  = (float*)d_ws;

  hipLaunchKernelGGL(pass_a, dim3(1024), dim3(256), 0, stream, k, kr, v, ws);
  hipLaunchKernelGGL(pass_b, dim3(520), dim3(256), 0, stream, ws);
  hipLaunchKernelGGL(pass_c, dim3(512), dim3(128), 0, stream, q, qr, k, kr, v, ws, out);
}

// Round 3
// 144.265 us; speedup vs baseline: 11.0229x; 11.0229x over previous
//
#include <hip/hip_runtime.h>

#define SEQ 4096
#define DIM 64
#define CHUNK 128
#define NC 32
#define EPSV 1e-10f
#define KS_OFF 4194304   // float offset of ksum region in ws

typedef __attribute__((ext_vector_type(8))) short s16x8;   // 8 bf16 (4 VGPRs)
typedef __attribute__((ext_vector_type(4))) float f32x4;   // MFMA C/D

__device__ __forceinline__ unsigned short f2bf(float f) {
  unsigned int u = __float_as_uint(f);
  u += 0x7FFF + ((u >> 16) & 1);          // RNE (inputs are finite)
  return (unsigned short)(u >> 16);
}
__device__ __forceinline__ float bf2f(unsigned short s) {
  return __uint_as_float(((unsigned int)s) << 16);
}

// ---------------- Pass A: S^T[e][d] = sum_j v[j][e] k[j][d] via MFMA ----------------
// ws S region: [2][16][32] chunks of 64x64 fp32 (S^T, row=e, col=d); ksum at KS_OFF.
__global__ __launch_bounds__(256) void pass_a(const float* __restrict__ k0,
                                              const float* __restrict__ k1,
                                              const float* __restrict__ v,
                                              float* __restrict__ ws) {
  __shared__ __align__(16) unsigned short skT[64 * 136];  // kT[d][j], row pad 136
  __shared__ __align__(16) unsigned short svT[64 * 136];  // vT[e][j]
  int bid = blockIdx.x;
  int m = bid >> 9, rem = bid & 511, hh = rem >> 5, c = rem & 31;
  const float* kp = (m ? k1 : k0) + (size_t)hh * SEQ * DIM + (size_t)c * CHUNK * DIM;
  const float* vp = v + (size_t)hh * SEQ * DIM + (size_t)c * CHUNK * DIM;
  int t = threadIdx.x;

  // stage transposed bf16 (coalesced global float4 reads; scattered b16 LDS writes)
  for (int pass = 0; pass < 8; ++pass) {
    int idx = t + pass * 256;            // 2048 float4 = 128x64 fp32
    int j = idx >> 4, e4 = idx & 15;
    float4 kk = ((const float4*)kp)[idx];
    float4 vv = ((const float4*)vp)[idx];
    int d0 = e4 * 4;
    skT[(d0 + 0) * 136 + j] = f2bf(kk.x);
    skT[(d0 + 1) * 136 + j] = f2bf(kk.y);
    skT[(d0 + 2) * 136 + j] = f2bf(kk.z);
    skT[(d0 + 3) * 136 + j] = f2bf(kk.w);
    svT[(d0 + 0) * 136 + j] = f2bf(vv.x);
    svT[(d0 + 1) * 136 + j] = f2bf(vv.y);
    svT[(d0 + 2) * 136 + j] = f2bf(vv.z);
    svT[(d0 + 3) * 136 + j] = f2bf(vv.w);
  }
  __syncthreads();

  // ksum[d] = sum_j k[j][d]  (row-sum of kT)
  if (t < 64) {
    float s = 0.f;
    for (int it = 0; it < 16; ++it) {
      s16x8 blk = *(const s16x8*)&skT[t * 136 + it * 8];
#pragma unroll
      for (int u = 0; u < 8; ++u) s += bf2f((unsigned short)blk[u]);
    }
    ws[KS_OFF + (size_t)bid * 64 + t] = s;
  }

  // MFMA: wave w -> e-tile w; A = vT (m=e), B = kT rows (k=j, n=d)
  int w = t >> 6, L = t & 63, g = L >> 4, cL = L & 15;
  f32x4 acc[4];
#pragma unroll
  for (int ct = 0; ct < 4; ++ct) acc[ct] = (f32x4){0.f, 0.f, 0.f, 0.f};
#pragma unroll
  for (int ks = 0; ks < 4; ++ks) {
    s16x8 aF = *(const s16x8*)&svT[(w * 16 + cL) * 136 + ks * 32 + g * 8];
#pragma unroll
    for (int ct = 0; ct < 4; ++ct) {
      s16x8 bF = *(const s16x8*)&skT[(ct * 16 + cL) * 136 + ks * 32 + g * 8];
      acc[ct] = __builtin_amdgcn_mfma_f32_16x16x32_bf16(aF, bF, acc[ct], 0, 0, 0);
    }
  }
  // C/D layout: col = cL (=d-local), row = g*4+r (=e-local)
  float* Sp = ws + (size_t)bid * 4096;
#pragma unroll
  for (int ct = 0; ct < 4; ++ct)
#pragma unroll
    for (int r = 0; r < 4; ++r)
      Sp[(size_t)(w * 16 + g * 4 + r) * 64 + ct * 16 + cL] = acc[ct][r];
}

// ---------------- Pass B: exclusive prefix over chunks (elementwise on S^T, ksum) ---
__global__ __launch_bounds__(256) void pass_b(float* __restrict__ ws) {
  int t = blockIdx.x * 256 + threadIdx.x;
  if (blockIdx.x < 512) {
    int mh = t >> 12, de = t & 4095;
    float* p = ws + (size_t)mh * NC * 4096 + de;
    float run = 0.f;
    for (int c = 0; c < NC; ++c) {
      float x = p[(size_t)c * 4096];
      p[(size_t)c * 4096] = run;
      run += x;
    }
  } else {
    int t2 = t - 512 * 256;
    int mh = t2 >> 6, d = t2 & 63;
    float* p = ws + KS_OFF + (size_t)mh * NC * 64 + d;
    float run = 0.f;
    for (int c = 0; c < NC; ++c) {
      float x = p[(size_t)c * 64];
      p[(size_t)c * 64] = run;
      run += x;
    }
  }
}

// ---------------- Pass C: per-chunk output via MFMA ----------------
// Block = 256 thr (4 waves); wave w owns rows 32w..32w+31 (row-tiles 2w, 2w+1).
__global__ __launch_bounds__(256) void pass_c(const float* __restrict__ q0,
                                              const float* __restrict__ q1,
                                              const float* __restrict__ k0,
                                              const float* __restrict__ k1,
                                              const float* __restrict__ v,
                                              const float* __restrict__ ws,
                                              float* __restrict__ out) {
  __shared__ __align__(16) unsigned short sq[128 * 72];   // q[i][d], pad 72
  __shared__ __align__(16) unsigned short skl[128 * 72];  // k[j][d], pad 72
  __shared__ __align__(16) unsigned short svT[64 * 136];  // vT[e][j], pad 136
  __shared__ __align__(16) unsigned short sU[5120];       // ST (64x72) then P strips (128x40, wave-private rows)
  __shared__ float sden[128];
  __shared__ float skpref[64];

  int hh = blockIdx.x >> 5, c = blockIdx.x & 31;
  int t = threadIdx.x;
  int w = t >> 6, L = t & 63, g = L >> 4, cL = L & 15;
  size_t off = (size_t)hh * SEQ * DIM + (size_t)c * CHUNK * DIM;

  // stage vT once (v shared by both maps)
  const float* vp = v + off;
  for (int pass = 0; pass < 8; ++pass) {
    int idx = t + pass * 256;
    int j = idx >> 4, e4 = idx & 15;
    float4 vv = ((const float4*)vp)[idx];
    int e0 = e4 * 4;
    svT[(e0 + 0) * 136 + j] = f2bf(vv.x);
    svT[(e0 + 1) * 136 + j] = f2bf(vv.y);
    svT[(e0 + 2) * 136 + j] = f2bf(vv.z);
    svT[(e0 + 3) * 136 + j] = f2bf(vv.w);
  }

  f32x4 accO[2][4];
#pragma unroll
  for (int a = 0; a < 2; ++a)
#pragma unroll
    for (int b = 0; b < 4; ++b) accO[a][b] = (f32x4){0.f, 0.f, 0.f, 0.f};
  float denfrag[2][4] = {};
  float denqk = 0.f;

  for (int m = 0; m < 2; ++m) {
    const float* qp = (m ? q1 : q0) + off;
    const float* kp = (m ? k1 : k0) + off;
    const float* Sp = ws + (size_t)(m * 512 + hh * 32 + c) * 4096;
    const float* Kp = ws + KS_OFF + (size_t)(m * 512 + hh * 32 + c) * 64;

    __syncthreads();  // previous map's strip reads / vT staging done
    for (int pass = 0; pass < 8; ++pass) {
      int idx = t + pass * 256;
      int i = idx >> 4, d4 = idx & 15;
      float4 qq = ((const float4*)qp)[idx];
      float4 kk = ((const float4*)kp)[idx];
      ushort4 uq = make_ushort4(f2bf(qq.x), f2bf(qq.y), f2bf(qq.z), f2bf(qq.w));
      ushort4 uk = make_ushort4(f2bf(kk.x), f2bf(kk.y), f2bf(kk.z), f2bf(kk.w));
      *(ushort4*)&sq[i * 72 + d4 * 4] = uq;
      *(ushort4*)&skl[i * 72 + d4 * 4] = uk;
    }
    for (int pass = 0; pass < 4; ++pass) {
      int idx = t + pass * 256;           // 1024 float4 = 64x64 fp32 S^T
      int e = idx >> 4, d4 = idx & 15;
      float4 ss = ((const float4*)Sp)[idx];
      ushort4 us = make_ushort4(f2bf(ss.x), f2bf(ss.y), f2bf(ss.z), f2bf(ss.w));
      *(ushort4*)&sU[e * 72 + d4 * 4] = us;
    }
    if (t < 64) skpref[t] = Kp[t];
    __syncthreads();

    // q A-frags for this wave's two row-tiles (held across strips)
    s16x8 aq[2][2];
#pragma unroll
    for (int rt01 = 0; rt01 < 2; ++rt01) {
      int row = (2 * w + rt01) * 16 + cL;
      aq[rt01][0] = *(const s16x8*)&sq[row * 72 + g * 8];
      aq[rt01][1] = *(const s16x8*)&sq[row * 72 + 32 + g * 8];
    }

    // den: q_i . ksum_prefix (thread-per-row, both maps accumulated)
    if (t < 128) {
      float s = 0.f;
      for (int it = 0; it < 8; ++it) {
        s16x8 blk = *(const s16x8*)&sq[t * 72 + it * 8];
#pragma unroll
        for (int u = 0; u < 8; ++u) s += bf2f((unsigned short)blk[u]) * skpref[it * 8 + u];
      }
      denqk += s;
    }

    // inter: O += q @ S_prefix  (B from ST rows: B[k=d][n=e] = ST[e][d])
#pragma unroll
    for (int h = 0; h < 2; ++h) {
#pragma unroll
      for (int et = 0; et < 4; ++et) {
        s16x8 bS = *(const s16x8*)&sU[(et * 16 + cL) * 72 + h * 32 + g * 8];
        accO[0][et] = __builtin_amdgcn_mfma_f32_16x16x32_bf16(aq[0][h], bS, accO[0][et], 0, 0, 0);
        accO[1][et] = __builtin_amdgcn_mfma_f32_16x16x32_bf16(aq[1][h], bS, accO[1][et], 0, 0, 0);
      }
    }
    __syncthreads();  // all ST reads complete before P strips overwrite sU

    // strips of 32 j's; wave w only needs s <= w (rest fully masked). No barriers inside.
    for (int s = 0; s <= w; ++s) {
      s16x8 bK[2][2];
#pragma unroll
      for (int ct01 = 0; ct01 < 2; ++ct01) {
        int jrow = (2 * s + ct01) * 16 + cL;
        bK[ct01][0] = *(const s16x8*)&skl[jrow * 72 + g * 8];
        bK[ct01][1] = *(const s16x8*)&skl[jrow * 72 + 32 + g * 8];
      }
#pragma unroll
      for (int rt01 = 0; rt01 < 2; ++rt01) {
        int rt = 2 * w + rt01;
        int rowbase = rt * 16 + g * 4;
#pragma unroll
        for (int ct01 = 0; ct01 < 2; ++ct01) {
          int jt = 2 * s + ct01;
          if (jt > rt) {  // fully masked tile: zero-fill P (still read by PV)
#pragma unroll
            for (int r = 0; r < 4; ++r) sU[(rowbase + r) * 40 + ct01 * 16 + cL] = 0;
          } else {
            f32x4 C = (f32x4){0.f, 0.f, 0.f, 0.f};
            C = __builtin_amdgcn_mfma_f32_16x16x32_bf16(aq[rt01][0], bK[ct01][0], C, 0, 0, 0);
            C = __builtin_amdgcn_mfma_f32_16x16x32_bf16(aq[rt01][1], bK[ct01][1], C, 0, 0, 0);
            if (jt == rt) {  // diagonal tile: keep col<=row (local: cL <= g*4+r)
#pragma unroll
              for (int r = 0; r < 4; ++r)
                if (cL > g * 4 + r) C[r] = 0.f;
            }
#pragma unroll
            for (int r = 0; r < 4; ++r) {
              denfrag[rt01][r] += C[r];
              sU[(rowbase + r) * 40 + ct01 * 16 + cL] = f2bf(C[r]);
            }
          }
        }
      }
      // P writes are wave-private rows; drain LDS before same-wave reload.
      asm volatile("s_waitcnt lgkmcnt(0)" ::: "memory");

      s16x8 bV[4];
#pragma unroll
      for (int et = 0; et < 4; ++et)
        bV[et] = *(const s16x8*)&svT[(et * 16 + cL) * 136 + s * 32 + g * 8];
#pragma unroll
      for (int rt01 = 0; rt01 < 2; ++rt01) {
        s16x8 aP = *(const s16x8*)&sU[((2 * w + rt01) * 16 + cL) * 40 + g * 8];
#pragma unroll
        for (int et = 0; et < 4; ++et)
          accO[rt01][et] = __builtin_amdgcn_mfma_f32_16x16x32_bf16(aP, bV[et], accO[rt01][et], 0, 0, 0);
      }
    }
  }

  if (t < 128) sden[t] = denqk;
  __syncthreads();

  // finalize: butterfly-reduce intra rowsums over the 16 col-lanes, scale, store
  float* op = out + off;
#pragma unroll
  for (int rt01 = 0; rt01 < 2; ++rt01) {
#pragma unroll
    for (int r = 0; r < 4; ++r) {
      float vs = denfrag[rt01][r];
      vs += __shfl_xor(vs, 1);
      vs += __shfl_xor(vs, 2);
      vs += __shfl_xor(vs, 4);
      vs += __shfl_xor(vs, 8);
      int row = (2 * w + rt01) * 16 + g * 4 + r;
      float inv = 1.f / (sden[row] + vs + EPSV);
#pragma unroll
      for (int et = 0; et < 4; ++et)
        op[(size_t)row * 64 + et * 16 + cL] = accO[rt01][et][r] * inv;
    }
  }
}

extern "C" void kernel_launch(void* const* d_in, const int* in_sizes, int n_in,
                              void* d_out, int out_size, void* d_ws, size_t ws_size,
                              hipStream_t stream) {
  const float* q  = (const float*)d_in[0];
  const float* k  = (const float*)d_in[1];
  const float* qr = (const float*)d_in[2];
  const float* kr = (const float*)d_in[3];
  const float* v  = (const float*)d_in[4];
  float* out = (float*)d_out;
  float* ws  = (float*)d_ws;

  hipLaunchKernelGGL(pass_a, dim3(1024), dim3(256), 0, stream, k, kr, v, ws);
  hipLaunchKernelGGL(pass_b, dim3(520), dim3(256), 0, stream, ws);
  hipLaunchKernelGGL(pass_c, dim3(512), dim3(256), 0, stream, q, qr, k, kr, v, ws, out);
}

// Round 4
// 143.661 us; speedup vs baseline: 11.0693x; 1.0042x over previous
//
#include <hip/hip_runtime.h>

#define SEQ 4096
#define DIM 64
#define CHUNK 128
#define NC 32
#define EPSV 1e-10f
#define KS_OFF 4194304   // float offset of ksum region in ws

typedef __attribute__((ext_vector_type(8))) short s16x8;   // 8 bf16 (4 VGPRs)
typedef __attribute__((ext_vector_type(4))) float f32x4;   // MFMA C/D

__device__ __forceinline__ unsigned short f2bf(float f) {
  unsigned int u = __float_as_uint(f);
  u += 0x7FFF + ((u >> 16) & 1);          // RNE (inputs are finite)
  return (unsigned short)(u >> 16);
}
__device__ __forceinline__ float bf2f(unsigned short s) {
  return __uint_as_float(((unsigned int)s) << 16);
}

// stage 128x64 fp32 global tile -> natural bf16 rows (stride 72 shorts).
// b64 writes: bank = (4i + 2d4) mod 32 -> 4-cycle structural minimum, conflict-free.
__device__ __forceinline__ void stage_nat(const float* __restrict__ gp,
                                          unsigned short* __restrict__ nat, int t) {
#pragma unroll
  for (int p = 0; p < 8; ++p) {
    int idx = t + p * 256;
    int i = idx >> 4, d4 = idx & 15;
    float4 x = ((const float4*)gp)[idx];
    ushort4 u = make_ushort4(f2bf(x.x), f2bf(x.y), f2bf(x.z), f2bf(x.w));
    *(ushort4*)&nat[i * 72 + d4 * 4] = u;
  }
}

// transpose natural (128 rows j x 64 cols d, stride 72) -> T (64 rows d x 128 cols j, stride 136).
// reads: lane d=L -> bank = 4u + d/2, all 32 banks (pairs share dword = broadcast): conflict-free.
// writes: b128, bank base 4L mod 32 -> 8-cycle minimum.
__device__ __forceinline__ void transpose_to_T(const unsigned short* __restrict__ nat,
                                               unsigned short* __restrict__ dst, int t) {
  int L = t & 63, w = t >> 6;
#pragma unroll
  for (int it = 0; it < 4; ++it) {
    int d = L, j8 = it * 4 + w;
    s16x8 seg;
#pragma unroll
    for (int u = 0; u < 8; ++u) seg[u] = (short)nat[(j8 * 8 + u) * 72 + d];
    *(s16x8*)&dst[d * 136 + j8 * 8] = seg;
  }
}

// ---------------- Pass A: S^T[e][d] = sum_j v[j][e] k[j][d] via MFMA ----------------
__global__ __launch_bounds__(256) void pass_a(const float* __restrict__ k0,
                                              const float* __restrict__ k1,
                                              const float* __restrict__ v,
                                              float* __restrict__ ws) {
  __shared__ __align__(16) unsigned short skT[64 * 136];   // kT[d][j]
  __shared__ __align__(16) unsigned short svT[64 * 136];   // vT[e][j]
  __shared__ __align__(16) unsigned short snat[128 * 72];  // natural staging
  int bid = blockIdx.x;
  int m = bid >> 9, rem = bid & 511, hh = rem >> 5, c = rem & 31;
  const float* kp = (m ? k1 : k0) + (size_t)hh * SEQ * DIM + (size_t)c * CHUNK * DIM;
  const float* vp = v + (size_t)hh * SEQ * DIM + (size_t)c * CHUNK * DIM;
  int t = threadIdx.x;

  stage_nat(kp, snat, t);
  __syncthreads();
  transpose_to_T(snat, skT, t);
  __syncthreads();
  stage_nat(vp, snat, t);
  __syncthreads();
  transpose_to_T(snat, svT, t);
  __syncthreads();

  // ksum[d] = sum_j k[j][d]  (row-sum of kT)
  if (t < 64) {
    float s = 0.f;
    for (int it = 0; it < 16; ++it) {
      s16x8 blk = *(const s16x8*)&skT[t * 136 + it * 8];
#pragma unroll
      for (int u = 0; u < 8; ++u) s += bf2f((unsigned short)blk[u]);
    }
    ws[KS_OFF + (size_t)bid * 64 + t] = s;
  }

  // MFMA: wave w -> e-tile w; A = vT (m=e), B = kT rows (k=j, n=d)
  int w = t >> 6, L = t & 63, g = L >> 4, cL = L & 15;
  f32x4 acc[4];
#pragma unroll
  for (int ct = 0; ct < 4; ++ct) acc[ct] = (f32x4){0.f, 0.f, 0.f, 0.f};
#pragma unroll
  for (int ks = 0; ks < 4; ++ks) {
    s16x8 aF = *(const s16x8*)&svT[(w * 16 + cL) * 136 + ks * 32 + g * 8];
#pragma unroll
    for (int ct = 0; ct < 4; ++ct) {
      s16x8 bF = *(const s16x8*)&skT[(ct * 16 + cL) * 136 + ks * 32 + g * 8];
      acc[ct] = __builtin_amdgcn_mfma_f32_16x16x32_bf16(aF, bF, acc[ct], 0, 0, 0);
    }
  }
  // C/D layout: col = cL (=d-local), row = g*4+r (=e-local)
  float* Sp = ws + (size_t)bid * 4096;
#pragma unroll
  for (int ct = 0; ct < 4; ++ct)
#pragma unroll
    for (int r = 0; r < 4; ++r)
      Sp[(size_t)(w * 16 + g * 4 + r) * 64 + ct * 16 + cL] = acc[ct][r];
}

// ---------------- Pass B: exclusive prefix over chunks ----------------
__global__ __launch_bounds__(256) void pass_b(float* __restrict__ ws) {
  int t = blockIdx.x * 256 + threadIdx.x;
  if (blockIdx.x < 512) {
    int mh = t >> 12, de = t & 4095;
    float* p = ws + (size_t)mh * NC * 4096 + de;
    float run = 0.f;
    for (int c = 0; c < NC; ++c) {
      float x = p[(size_t)c * 4096];
      p[(size_t)c * 4096] = run;
      run += x;
    }
  } else {
    int t2 = t - 512 * 256;
    int mh = t2 >> 6, d = t2 & 63;
    float* p = ws + KS_OFF + (size_t)mh * NC * 64 + d;
    float run = 0.f;
    for (int c = 0; c < NC; ++c) {
      float x = p[(size_t)c * 64];
      p[(size_t)c * 64] = run;
      run += x;
    }
  }
}

// ---------------- Pass C: per-chunk output via MFMA ----------------
// 4 waves; wave w owns row-tiles {w, 7-w} (balanced causal work: 9 score-units/wave).
__global__ __launch_bounds__(256) void pass_c(const float* __restrict__ q0,
                                              const float* __restrict__ q1,
                                              const float* __restrict__ k0,
                                              const float* __restrict__ k1,
                                              const float* __restrict__ v,
                                              const float* __restrict__ ws,
                                              float* __restrict__ out) {
  __shared__ __align__(16) unsigned short sq[128 * 72];   // q[i][d]
  __shared__ __align__(16) unsigned short skl[128 * 72];  // v-natural stage, then k[j][d]
  __shared__ __align__(16) unsigned short svT[64 * 136];  // vT[e][j]
  __shared__ __align__(16) unsigned short sU[5120];       // ST (64x72) then P strips (128x40)
  __shared__ float sden[128];
  __shared__ float skpref[64];

  int hh = blockIdx.x >> 5, c = blockIdx.x & 31;
  int t = threadIdx.x;
  int w = t >> 6, L = t & 63, g = L >> 4, cL = L & 15;
  size_t off = (size_t)hh * SEQ * DIM + (size_t)c * CHUNK * DIM;
  int rt_of[2] = {w, 7 - w};

  // stage v: natural into skl, then conflict-free transpose into svT
  stage_nat(v + off, skl, t);
  __syncthreads();
  transpose_to_T(skl, svT, t);

  f32x4 accO[2][4];
#pragma unroll
  for (int a = 0; a < 2; ++a)
#pragma unroll
    for (int b = 0; b < 4; ++b) accO[a][b] = (f32x4){0.f, 0.f, 0.f, 0.f};
  float denfrag[2][4] = {};
  float denqk = 0.f;

  for (int m = 0; m < 2; ++m) {
    const float* qp = (m ? q1 : q0) + off;
    const float* kp = (m ? k1 : k0) + off;
    const float* Sp = ws + (size_t)(m * 512 + hh * 32 + c) * 4096;
    const float* Kp = ws + KS_OFF + (size_t)(m * 512 + hh * 32 + c) * 64;

    __syncthreads();  // svT transpose reads of skl done / previous map's strip reads done
    stage_nat(qp, sq, t);
    stage_nat(kp, skl, t);
#pragma unroll
    for (int pass = 0; pass < 4; ++pass) {
      int idx = t + pass * 256;           // 1024 float4 = 64x64 fp32 S^T
      int e = idx >> 4, d4 = idx & 15;
      float4 ss = ((const float4*)Sp)[idx];
      ushort4 us = make_ushort4(f2bf(ss.x), f2bf(ss.y), f2bf(ss.z), f2bf(ss.w));
      *(ushort4*)&sU[e * 72 + d4 * 4] = us;
    }
    if (t < 64) skpref[t] = Kp[t];
    __syncthreads();

    // q A-frags for this wave's two row-tiles
    s16x8 aq[2][2];
#pragma unroll
    for (int ti = 0; ti < 2; ++ti) {
      int row = rt_of[ti] * 16 + cL;
      aq[ti][0] = *(const s16x8*)&sq[row * 72 + g * 8];
      aq[ti][1] = *(const s16x8*)&sq[row * 72 + 32 + g * 8];
    }

    // den: q_i . ksum_prefix (thread-per-row)
    if (t < 128) {
      float s = 0.f;
      for (int it = 0; it < 8; ++it) {
        s16x8 blk = *(const s16x8*)&sq[t * 72 + it * 8];
#pragma unroll
        for (int u = 0; u < 8; ++u) s += bf2f((unsigned short)blk[u]) * skpref[it * 8 + u];
      }
      denqk += s;
    }

    // inter: O += q @ S_prefix  (B from ST rows)
#pragma unroll
    for (int h = 0; h < 2; ++h) {
#pragma unroll
      for (int et = 0; et < 4; ++et) {
        s16x8 bS = *(const s16x8*)&sU[(et * 16 + cL) * 72 + h * 32 + g * 8];
        accO[0][et] = __builtin_amdgcn_mfma_f32_16x16x32_bf16(aq[0][h], bS, accO[0][et], 0, 0, 0);
        accO[1][et] = __builtin_amdgcn_mfma_f32_16x16x32_bf16(aq[1][h], bS, accO[1][et], 0, 0, 0);
      }
    }
    __syncthreads();  // all ST reads complete before P strips overwrite sU

    // strips of 32 j's. Wave-uniform bounds; tiles {w, 7-w} give balanced work.
    for (int s = 0; s <= (7 - w) >> 1; ++s) {
      s16x8 bK[2][2];
#pragma unroll
      for (int ct01 = 0; ct01 < 2; ++ct01) {
        int jrow = (2 * s + ct01) * 16 + cL;
        bK[ct01][0] = *(const s16x8*)&skl[jrow * 72 + g * 8];
        bK[ct01][1] = *(const s16x8*)&skl[jrow * 72 + 32 + g * 8];
      }
#pragma unroll
      for (int ti = 0; ti < 2; ++ti) {
        int rt = rt_of[ti];
        if (2 * s > rt) continue;          // tile inactive this strip (wave-uniform)
        int rowbase = rt * 16 + g * 4;
#pragma unroll
        for (int ct01 = 0; ct01 < 2; ++ct01) {
          int jt = 2 * s + ct01;
          if (jt > rt) {                   // fully masked half: zero-fill P
#pragma unroll
            for (int r = 0; r < 4; ++r) sU[(rowbase + r) * 40 + ct01 * 16 + cL] = 0;
          } else {
            f32x4 C = (f32x4){0.f, 0.f, 0.f, 0.f};
            C = __builtin_amdgcn_mfma_f32_16x16x32_bf16(aq[ti][0], bK[ct01][0], C, 0, 0, 0);
            C = __builtin_amdgcn_mfma_f32_16x16x32_bf16(aq[ti][1], bK[ct01][1], C, 0, 0, 0);
            if (jt == rt) {                // diagonal tile: keep col<=row
#pragma unroll
              for (int r = 0; r < 4; ++r)
                if (cL > g * 4 + r) C[r] = 0.f;
            }
#pragma unroll
            for (int r = 0; r < 4; ++r) {
              denfrag[ti][r] += C[r];
              sU[(rowbase + r) * 40 + ct01 * 16 + cL] = f2bf(C[r]);
            }
          }
        }
      }
      // P writes are wave-private rows; drain LDS before same-wave reload.
      asm volatile("s_waitcnt lgkmcnt(0)" ::: "memory");

      s16x8 bV[4];
#pragma unroll
      for (int et = 0; et < 4; ++et)
        bV[et] = *(const s16x8*)&svT[(et * 16 + cL) * 136 + s * 32 + g * 8];
#pragma unroll
      for (int ti = 0; ti < 2; ++ti) {
        if (2 * s > rt_of[ti]) continue;
        s16x8 aP = *(const s16x8*)&sU[(rt_of[ti] * 16 + cL) * 40 + g * 8];
#pragma unroll
        for (int et = 0; et < 4; ++et)
          accO[ti][et] = __builtin_amdgcn_mfma_f32_16x16x32_bf16(aP, bV[et], accO[ti][et], 0, 0, 0);
      }
    }
  }

  if (t < 128) sden[t] = denqk;
  __syncthreads();

  // finalize: butterfly-reduce intra rowsums over the 16 col-lanes, scale, store
  float* op = out + off;
#pragma unroll
  for (int ti = 0; ti < 2; ++ti) {
#pragma unroll
    for (int r = 0; r < 4; ++r) {
      float vs = denfrag[ti][r];
      vs += __shfl_xor(vs, 1);
      vs += __shfl_xor(vs, 2);
      vs += __shfl_xor(vs, 4);
      vs += __shfl_xor(vs, 8);
      int row = rt_of[ti] * 16 + g * 4 + r;
      float inv = 1.f / (sden[row] + vs + EPSV);
#pragma unroll
      for (int et = 0; et < 4; ++et)
        op[(size_t)row * 64 + et * 16 + cL] = accO[ti][et][r] * inv;
    }
  }
}

extern "C" void kernel_launch(void* const* d_in, const int* in_sizes, int n_in,
                              void* d_out, int out_size, void* d_ws, size_t ws_size,
                              hipStream_t stream) {
  const float* q  = (const float*)d_in[0];
  const float* k  = (const float*)d_in[1];
  const float* qr = (const float*)d_in[2];
  const float* kr = (const float*)d_in[3];
  const float* v  = (const float*)d_in[4];
  float* out = (float*)d_out;
  float* ws  = (float*)d_ws;

  hipLaunchKernelGGL(pass_a, dim3(1024), dim3(256), 0, stream, k, kr, v, ws);
  hipLaunchKernelGGL(pass_b, dim3(520), dim3(256), 0, stream, ws);
  hipLaunchKernelGGL(pass_c, dim3(512), dim3(256), 0, stream, q, qr, k, kr, v, ws, out);
}

// Round 5
// 140.401 us; speedup vs baseline: 11.3263x; 1.0232x over previous
//
#include <hip/hip_runtime.h>

#define SEQ 4096
#define DIM 64
#define CHUNK 128
#define NC 32
#define EPSV 1e-10f
#define KS_OFF 2097152   // float offset of ksum region (S region = 1024 chunks * 4096 bf16 = 8 MiB)

typedef __attribute__((ext_vector_type(8))) short s16x8;   // 8 bf16 (4 VGPRs)
typedef __attribute__((ext_vector_type(4))) float f32x4;   // MFMA C/D

__device__ __forceinline__ unsigned short f2bf(float f) {
  unsigned int u = __float_as_uint(f);
  u += 0x7FFF + ((u >> 16) & 1);          // RNE (inputs are finite)
  return (unsigned short)(u >> 16);
}
__device__ __forceinline__ float bf2f(unsigned short s) {
  return __uint_as_float(((unsigned int)s) << 16);
}
__device__ __forceinline__ s16x8 pack8(float4 a, float4 b) {
  s16x8 r;
  r[0] = (short)f2bf(a.x); r[1] = (short)f2bf(a.y); r[2] = (short)f2bf(a.z); r[3] = (short)f2bf(a.w);
  r[4] = (short)f2bf(b.x); r[5] = (short)f2bf(b.y); r[6] = (short)f2bf(b.z); r[7] = (short)f2bf(b.w);
  return r;
}

// stage 128x64 fp32 global tile -> natural bf16 rows (stride 72 shorts). Conflict-free b64 writes.
__device__ __forceinline__ void stage_nat(const float* __restrict__ gp,
                                          unsigned short* __restrict__ nat, int t) {
#pragma unroll
  for (int p = 0; p < 8; ++p) {
    int idx = t + p * 256;
    int i = idx >> 4, d4 = idx & 15;
    float4 x = ((const float4*)gp)[idx];
    ushort4 u = make_ushort4(f2bf(x.x), f2bf(x.y), f2bf(x.z), f2bf(x.w));
    *(ushort4*)&nat[i * 72 + d4 * 4] = u;
  }
}

// transpose natural (128 x 64, stride 72) -> T (64 x 128, stride 136). Conflict-free.
__device__ __forceinline__ void transpose_to_T(const unsigned short* __restrict__ nat,
                                               unsigned short* __restrict__ dst, int t) {
  int L = t & 63, w = t >> 6;
#pragma unroll
  for (int it = 0; it < 4; ++it) {
    int d = L, j8 = it * 4 + w;
    s16x8 seg;
#pragma unroll
    for (int u = 0; u < 8; ++u) seg[u] = (short)nat[(j8 * 8 + u) * 72 + d];
    *(s16x8*)&dst[d * 136 + j8 * 8] = seg;
  }
}

// ---------------- Pass A: S^T[e][d] = sum_j v[j][e] k[j][d] via MFMA; store bf16 ----------------
__global__ __launch_bounds__(256) void pass_a(const float* __restrict__ k0,
                                              const float* __restrict__ k1,
                                              const float* __restrict__ v,
                                              float* __restrict__ ws) {
  __shared__ __align__(16) unsigned short skT[64 * 136];   // kT[d][j]
  __shared__ __align__(16) unsigned short svT[64 * 136];   // vT[e][j]
  __shared__ __align__(16) unsigned short snat[128 * 72];  // natural staging
  int bid = blockIdx.x;
  int m = bid >> 9, rem = bid & 511, hh = rem >> 5, c = rem & 31;
  const float* kp = (m ? k1 : k0) + (size_t)hh * SEQ * DIM + (size_t)c * CHUNK * DIM;
  const float* vp = v + (size_t)hh * SEQ * DIM + (size_t)c * CHUNK * DIM;
  int t = threadIdx.x;

  stage_nat(kp, snat, t);
  __syncthreads();
  transpose_to_T(snat, skT, t);
  __syncthreads();
  stage_nat(vp, snat, t);
  __syncthreads();
  transpose_to_T(snat, svT, t);
  __syncthreads();

  // ksum[d] = sum_j k[j][d]  (row-sum of kT)
  if (t < 64) {
    float s = 0.f;
    for (int it = 0; it < 16; ++it) {
      s16x8 blk = *(const s16x8*)&skT[t * 136 + it * 8];
#pragma unroll
      for (int u = 0; u < 8; ++u) s += bf2f((unsigned short)blk[u]);
    }
    ws[KS_OFF + (size_t)bid * 64 + t] = s;
  }

  // MFMA: wave w -> e-tile w; A = vT (m=e), B = kT rows (k=j, n=d)
  int w = t >> 6, L = t & 63, g = L >> 4, cL = L & 15;
  f32x4 acc[4];
#pragma unroll
  for (int ct = 0; ct < 4; ++ct) acc[ct] = (f32x4){0.f, 0.f, 0.f, 0.f};
#pragma unroll
  for (int ks = 0; ks < 4; ++ks) {
    s16x8 aF = *(const s16x8*)&svT[(w * 16 + cL) * 136 + ks * 32 + g * 8];
#pragma unroll
    for (int ct = 0; ct < 4; ++ct) {
      s16x8 bF = *(const s16x8*)&skT[(ct * 16 + cL) * 136 + ks * 32 + g * 8];
      acc[ct] = __builtin_amdgcn_mfma_f32_16x16x32_bf16(aF, bF, acc[ct], 0, 0, 0);
    }
  }
  // C/D layout: col = cL (=d-local), row = g*4+r (=e-local); store bf16
  unsigned short* Sp = (unsigned short*)ws + (size_t)bid * 4096;
#pragma unroll
  for (int ct = 0; ct < 4; ++ct)
#pragma unroll
    for (int r = 0; r < 4; ++r)
      Sp[(size_t)(w * 16 + g * 4 + r) * 64 + ct * 16 + cL] = f2bf(acc[ct][r]);
}

// ---------------- Pass B: exclusive prefix over chunks; all 32 loads in flight ----------------
// Blocks 0..255: S region (u32 = 2 bf16 lanes). Blocks 256..263: ksum (fp32).
__global__ __launch_bounds__(256) void pass_b(float* __restrict__ ws) {
  int t = threadIdx.x;
  if (blockIdx.x < 256) {
    int gid = blockIdx.x * 256 + t;            // [0, 65536)
    int mh = gid >> 11, de2 = gid & 2047;      // mh in [0,32)
    unsigned int* p = (unsigned int*)ws + (size_t)mh * NC * 2048 + de2;
    unsigned int x[NC];
#pragma unroll
    for (int c = 0; c < NC; ++c) x[c] = p[(size_t)c * 2048];
    float r0 = 0.f, r1 = 0.f;
#pragma unroll
    for (int c = 0; c < NC; ++c) {
      unsigned int xc = x[c];
      p[(size_t)c * 2048] = (unsigned int)f2bf(r0) | ((unsigned int)f2bf(r1) << 16);
      r0 += bf2f((unsigned short)(xc & 0xFFFF));
      r1 += bf2f((unsigned short)(xc >> 16));
    }
  } else {
    int gid = (blockIdx.x - 256) * 256 + t;    // [0, 2048)
    int mh = gid >> 6, d = gid & 63;
    float* p = ws + KS_OFF + (size_t)mh * NC * 64 + d;
    float x[NC];
#pragma unroll
    for (int c = 0; c < NC; ++c) x[c] = p[(size_t)c * 64];
    float run = 0.f;
#pragma unroll
    for (int c = 0; c < NC; ++c) {
      p[(size_t)c * 64] = run;
      run += x[c];
    }
  }
}

// ---------------- Pass C: per-chunk output via MFMA ----------------
// 4 waves; wave w owns row-tiles {w, 7-w}. q/k fragments loaded DIRECT from global (no LDS stage).
// LDS: svT (17 KiB) + sun union buffer (18 KiB: v-natural, then ST rows stride 72 / P strips stride 40).
__global__ __launch_bounds__(256) void pass_c(const float* __restrict__ q0,
                                              const float* __restrict__ q1,
                                              const float* __restrict__ k0,
                                              const float* __restrict__ k1,
                                              const float* __restrict__ v,
                                              const float* __restrict__ ws,
                                              float* __restrict__ out) {
  __shared__ __align__(16) unsigned short svT[64 * 136];
  __shared__ __align__(16) unsigned short sun[128 * 72];
  __shared__ float skpref[64];
  __shared__ float sden[128];

  int hh = blockIdx.x >> 5, c = blockIdx.x & 31;
  int t = threadIdx.x;
  int w = t >> 6, L = t & 63, g = L >> 4, cL = L & 15;
  size_t off = (size_t)hh * SEQ * DIM + (size_t)c * CHUNK * DIM;
  int rt_of[2] = {w, 7 - w};

  stage_nat(v + off, sun, t);
  __syncthreads();
  transpose_to_T(sun, svT, t);

  f32x4 accO[2][4];
#pragma unroll
  for (int a = 0; a < 2; ++a)
#pragma unroll
    for (int b = 0; b < 4; ++b) accO[a][b] = (f32x4){0.f, 0.f, 0.f, 0.f};
  float denfrag[2][4] = {};
  float denp[2] = {0.f, 0.f};

  const unsigned short* Sbase = (const unsigned short*)ws;

  for (int m = 0; m < 2; ++m) {
    const float* qp = (m ? q1 : q0) + off;
    const float* kp = (m ? k1 : k0) + off;
    const unsigned short* Sp = Sbase + (size_t)(m * 512 + hh * 32 + c) * 4096;
    const float* Kp = ws + KS_OFF + (size_t)(m * 512 + hh * 32 + c) * 64;

    __syncthreads();  // m=0: sun transpose-reads done; m=1: previous P reads done
    // stage ST (already bf16): rows stride 72
#pragma unroll
    for (int p2 = 0; p2 < 2; ++p2) {
      int idx = t + p2 * 256;            // 512 x 16B covers 64x64 bf16
      int e = idx >> 3, seg = idx & 7;
      *(s16x8*)&sun[e * 72 + seg * 8] = *(const s16x8*)&Sp[idx * 8];
    }
    if (t < 64) skpref[t] = Kp[t];
    __syncthreads();

    // ksum_prefix fragment (same d-range for both row-tiles)
    float kpf[2][8];
#pragma unroll
    for (int h = 0; h < 2; ++h) {
      float4 c0 = *(const float4*)&skpref[h * 32 + g * 8];
      float4 c1 = *(const float4*)&skpref[h * 32 + g * 8 + 4];
      kpf[h][0] = c0.x; kpf[h][1] = c0.y; kpf[h][2] = c0.z; kpf[h][3] = c0.w;
      kpf[h][4] = c1.x; kpf[h][5] = c1.y; kpf[h][6] = c1.z; kpf[h][7] = c1.w;
    }

    // q A-frags direct from global; den partial with fp32 q
    s16x8 aq[2][2];
#pragma unroll
    for (int ti = 0; ti < 2; ++ti) {
      int row = rt_of[ti] * 16 + cL;
#pragma unroll
      for (int h = 0; h < 2; ++h) {
        const float* qa = qp + row * 64 + h * 32 + g * 8;
        float4 a0 = *(const float4*)qa;
        float4 a1 = *(const float4*)(qa + 4);
        denp[ti] += a0.x * kpf[h][0] + a0.y * kpf[h][1] + a0.z * kpf[h][2] + a0.w * kpf[h][3]
                  + a1.x * kpf[h][4] + a1.y * kpf[h][5] + a1.z * kpf[h][6] + a1.w * kpf[h][7];
        aq[ti][h] = pack8(a0, a1);
      }
    }

    // inter: O += q @ S_prefix
#pragma unroll
    for (int h = 0; h < 2; ++h) {
#pragma unroll
      for (int et = 0; et < 4; ++et) {
        s16x8 bS = *(const s16x8*)&sun[(et * 16 + cL) * 72 + h * 32 + g * 8];
        accO[0][et] = __builtin_amdgcn_mfma_f32_16x16x32_bf16(aq[0][h], bS, accO[0][et], 0, 0, 0);
        accO[1][et] = __builtin_amdgcn_mfma_f32_16x16x32_bf16(aq[1][h], bS, accO[1][et], 0, 0, 0);
      }
    }
    __syncthreads();  // ST reads complete before P strips overwrite sun

    // strips of 32 j's; k B-frags direct from global
    for (int s = 0; s <= (7 - w) >> 1; ++s) {
      s16x8 bK[2][2];
#pragma unroll
      for (int ct01 = 0; ct01 < 2; ++ct01) {
        int jrow = (2 * s + ct01) * 16 + cL;
#pragma unroll
        for (int h = 0; h < 2; ++h) {
          const float* ka = kp + jrow * 64 + h * 32 + g * 8;
          float4 b0 = *(const float4*)ka;
          float4 b1 = *(const float4*)(ka + 4);
          bK[ct01][h] = pack8(b0, b1);
        }
      }
#pragma unroll
      for (int ti = 0; ti < 2; ++ti) {
        int rt = rt_of[ti];
        if (2 * s > rt) continue;          // wave-uniform
        int rowbase = rt * 16 + g * 4;
#pragma unroll
        for (int ct01 = 0; ct01 < 2; ++ct01) {
          int jt = 2 * s + ct01;
          if (jt > rt) {                   // fully masked half: zero-fill P
#pragma unroll
            for (int r = 0; r < 4; ++r) sun[(rowbase + r) * 40 + ct01 * 16 + cL] = 0;
          } else {
            f32x4 C = (f32x4){0.f, 0.f, 0.f, 0.f};
            C = __builtin_amdgcn_mfma_f32_16x16x32_bf16(aq[ti][0], bK[ct01][0], C, 0, 0, 0);
            C = __builtin_amdgcn_mfma_f32_16x16x32_bf16(aq[ti][1], bK[ct01][1], C, 0, 0, 0);
            if (jt == rt) {                // diagonal: keep col<=row
#pragma unroll
              for (int r = 0; r < 4; ++r)
                if (cL > g * 4 + r) C[r] = 0.f;
            }
#pragma unroll
            for (int r = 0; r < 4; ++r) {
              denfrag[ti][r] += C[r];
              sun[(rowbase + r) * 40 + ct01 * 16 + cL] = f2bf(C[r]);
            }
          }
        }
      }
      asm volatile("s_waitcnt lgkmcnt(0)" ::: "memory");  // wave-private P rows visible

      s16x8 bV[4];
#pragma unroll
      for (int et = 0; et < 4; ++et)
        bV[et] = *(const s16x8*)&svT[(et * 16 + cL) * 136 + s * 32 + g * 8];
#pragma unroll
      for (int ti = 0; ti < 2; ++ti) {
        if (2 * s > rt_of[ti]) continue;
        s16x8 aP = *(const s16x8*)&sun[(rt_of[ti] * 16 + cL) * 40 + g * 8];
#pragma unroll
        for (int et = 0; et < 4; ++et)
          accO[ti][et] = __builtin_amdgcn_mfma_f32_16x16x32_bf16(aP, bV[et], accO[ti][et], 0, 0, 0);
      }
    }
  }

  // reduce den over the 4 g-lanes (full d coverage), publish per row
#pragma unroll
  for (int ti = 0; ti < 2; ++ti) {
    denp[ti] += __shfl_xor(denp[ti], 16);
    denp[ti] += __shfl_xor(denp[ti], 32);
  }
  if (L < 16) {
    sden[rt_of[0] * 16 + L] = denp[0];
    sden[rt_of[1] * 16 + L] = denp[1];
  }
  __syncthreads();

  // finalize: butterfly intra rowsums over 16 col-lanes, scale, store
  float* op = out + off;
#pragma unroll
  for (int ti = 0; ti < 2; ++ti) {
#pragma unroll
    for (int r = 0; r < 4; ++r) {
      float vs = denfrag[ti][r];
      vs += __shfl_xor(vs, 1);
      vs += __shfl_xor(vs, 2);
      vs += __shfl_xor(vs, 4);
      vs += __shfl_xor(vs, 8);
      int row = rt_of[ti] * 16 + g * 4 + r;
      float inv = 1.f / (sden[row] + vs + EPSV);
#pragma unroll
      for (int et = 0; et < 4; ++et)
        op[(size_t)row * 64 + et * 16 + cL] = accO[ti][et][r] * inv;
    }
  }
}

extern "C" void kernel_launch(void* const* d_in, const int* in_sizes, int n_in,
                              void* d_out, int out_size, void* d_ws, size_t ws_size,
                              hipStream_t stream) {
  const float* q  = (const float*)d_in[0];
  const float* k  = (const float*)d_in[1];
  const float* qr = (const float*)d_in[2];
  const float* kr = (const float*)d_in[3];
  const float* v  = (const float*)d_in[4];
  float* out = (float*)d_out;
  float* ws  = (float*)d_ws;

  hipLaunchKernelGGL(pass_a, dim3(1024), dim3(256), 0, stream, k, kr, v, ws);
  hipLaunchKernelGGL(pass_b, dim3(264), dim3(256), 0, stream, ws);
  hipLaunchKernelGGL(pass_c, dim3(512), dim3(256), 0, stream, q, qr, k, kr, v, ws, out);
}